// Round 1
// baseline (1379.883 us; speedup 1.0000x reference)
//
#include <hip/hip_runtime.h>
#include <hip/hip_bf16.h>
#include <cstdio>

// MoE MLP (top-2 of 8 experts), D=1024, FF=4096, 8192 tokens, fp32 in/out.
// Pipeline: router -> prefix -> grouped GEMM1 (x@wfc + bfc, gelu) -> h(bf16)
//           -> grouped GEMM2 (h@wproj + bproj, gate, atomicAdd into out).
// GEMMs use mfma_f32_16x16x32_bf16 with fp32 accumulation.

#define N_TOK 8192
#define DMODEL 1024
#define NEXP 8
#define DFF 4096
#define CAP 8192   // max tokens per expert (each token in an expert list at most once)

typedef __attribute__((ext_vector_type(8))) short short8;
typedef __attribute__((ext_vector_type(4))) float f32x4;

__device__ __forceinline__ unsigned short f2bf(float f) {
  unsigned u = __float_as_uint(f);
  return (unsigned short)((u + 0x7FFFu + ((u >> 16) & 1u)) >> 16);  // RNE
}

__device__ __forceinline__ float gelu_f(float v) {
  return 0.5f * v * (1.0f + erff(v * 0.70710678118654752f));
}

__device__ __forceinline__ short8 pack8(float f0, float f1, float f2, float f3,
                                        float f4, float f5, float f6, float f7) {
  short8 r;
  r[0] = (short)f2bf(f0); r[1] = (short)f2bf(f1);
  r[2] = (short)f2bf(f2); r[3] = (short)f2bf(f3);
  r[4] = (short)f2bf(f4); r[5] = (short)f2bf(f5);
  r[6] = (short)f2bf(f6); r[7] = (short)f2bf(f7);
  return r;
}

// ---------------- Router: 1 wave per token ----------------
__global__ void router_k(const float* __restrict__ x, const float* __restrict__ rw,
                         int* __restrict__ cnt, int* __restrict__ tok,
                         float* __restrict__ gate) {
  int lane = threadIdx.x & 63;
  int t = blockIdx.x * 4 + (threadIdx.x >> 6);
  const float* xr = x + (size_t)t * DMODEL;
  float p[8];
#pragma unroll
  for (int e = 0; e < 8; ++e) p[e] = 0.0f;
#pragma unroll
  for (int j = 0; j < DMODEL / 64; ++j) {
    int i = lane + j * 64;
    float xv = xr[i];
    const float4* r = (const float4*)(rw + (size_t)i * 8);
    float4 a = r[0], b = r[1];
    p[0] += xv * a.x; p[1] += xv * a.y; p[2] += xv * a.z; p[3] += xv * a.w;
    p[4] += xv * b.x; p[5] += xv * b.y; p[6] += xv * b.z; p[7] += xv * b.w;
  }
#pragma unroll
  for (int e = 0; e < 8; ++e) {
#pragma unroll
    for (int off = 32; off; off >>= 1) p[e] += __shfl_xor(p[e], off, 64);
  }
  if (lane == 0) {
    int e1 = 0;
#pragma unroll
    for (int e = 1; e < 8; ++e) if (p[e] > p[e1]) e1 = e;  // strict >: ties -> lowest idx
    int e2 = (e1 == 0) ? 1 : 0;
#pragma unroll
    for (int e = 0; e < 8; ++e) if (e != e1 && p[e] > p[e2]) e2 = e;
    // softmax top-2 normalized: w1 = p1/(p1+p2) = 1/(1+exp(l2-l1))
    float w1 = 1.0f / (1.0f + expf(p[e2] - p[e1]));
    float w2 = 1.0f - w1;
    int s1 = atomicAdd(&cnt[e1], 1);
    tok[e1 * CAP + s1] = t; gate[e1 * CAP + s1] = w1;
    int s2 = atomicAdd(&cnt[e2], 1);
    tok[e2 * CAP + s2] = t; gate[e2 * CAP + s2] = w2;
  }
}

__global__ void prefix_k(const int* __restrict__ cnt, int* __restrict__ off) {
  if (threadIdx.x == 0 && blockIdx.x == 0) {
    int s = 0;
    for (int e = 0; e < NEXP; ++e) { off[e] = s; s += cnt[e]; }
  }
}

// ---------------- GEMM1: h = gelu(X_gathered @ wfc[e] + bfc[e]) ----------------
// 128x128 tile, BK=32, 4 waves each 64x64 (4x4 frags of 16x16x32).
__global__ __launch_bounds__(256, 2) void gemm1_k(
    const float* __restrict__ x, const float* __restrict__ wfc,
    const float* __restrict__ bfc, const int* __restrict__ cnt,
    const int* __restrict__ off, const int* __restrict__ tok,
    unsigned short* __restrict__ h) {
  int bid = blockIdx.x;
  int mt = bid & 63;
  int nt = (bid >> 6) & 31;
  int e = bid >> 11;
  int Me = cnt[e];
  if (mt * 128 >= Me) return;
  int base = off[e];
  int n0 = nt * 128;

  __shared__ __align__(16) unsigned short Als[128][40];  // [row][k], +8 pad (2-way free)
  __shared__ __align__(16) unsigned short Bls[128][40];  // [n][k] (transposed at staging)

  int tid = threadIdx.x;
  // A staging: thread -> (row, half of 32-wide k-slab)
  int rowA = tid >> 1, halfA = tid & 1;
  int tIdx = mt * 128 + rowA;
  int tokn = tok[e * CAP + ((tIdx < Me) ? tIdx : 0)];  // clamp: tail rows read row 0
  const float* srcA = x + (size_t)tokn * DMODEL + halfA * 16;
  unsigned short* wA = &Als[rowA][halfA * 16];
  // B staging: thread -> (n, k-half); 16 strided dword loads transpose wfc[k][n]->Bls[n][k]
  int nB = tid & 127, khB = tid >> 7;
  const float* srcB = wfc + (size_t)e * DMODEL * DFF + (size_t)(khB * 16) * DFF + n0 + nB;
  unsigned short* wB = &Bls[nB][khB * 16];

  int lane = tid & 63;
  int w = tid >> 6;
  int wr = w >> 1, wc = w & 1;
  int g = lane >> 4, fr = lane & 15;
  const unsigned short* rA[4];
  const unsigned short* rB[4];
#pragma unroll
  for (int i = 0; i < 4; ++i) {
    rA[i] = &Als[wr * 64 + i * 16 + fr][g * 8];
    rB[i] = &Bls[wc * 64 + i * 16 + fr][g * 8];
  }
  f32x4 acc[4][4];
#pragma unroll
  for (int i = 0; i < 4; ++i)
#pragma unroll
    for (int j = 0; j < 4; ++j) acc[i][j] = (f32x4)0.0f;

#pragma unroll 1
  for (int k0 = 0; k0 < DMODEL; k0 += 32) {
    const float4* pa = (const float4*)(srcA + k0);
    float4 a0 = pa[0], a1 = pa[1], a2 = pa[2], a3 = pa[3];
    float vb[16];
#pragma unroll
    for (int j = 0; j < 16; ++j) vb[j] = srcB[(size_t)(k0 + j) * DFF];
    short8 A0 = pack8(a0.x, a0.y, a0.z, a0.w, a1.x, a1.y, a1.z, a1.w);
    short8 A1 = pack8(a2.x, a2.y, a2.z, a2.w, a3.x, a3.y, a3.z, a3.w);
    short8 B0 = pack8(vb[0], vb[1], vb[2], vb[3], vb[4], vb[5], vb[6], vb[7]);
    short8 B1 = pack8(vb[8], vb[9], vb[10], vb[11], vb[12], vb[13], vb[14], vb[15]);
    *(short8*)wA = A0; *(short8*)(wA + 8) = A1;
    *(short8*)wB = B0; *(short8*)(wB + 8) = B1;
    __syncthreads();
    short8 af[4], bf_[4];
#pragma unroll
    for (int i = 0; i < 4; ++i) af[i] = *(const short8*)rA[i];
#pragma unroll
    for (int i = 0; i < 4; ++i) bf_[i] = *(const short8*)rB[i];
#pragma unroll
    for (int mi = 0; mi < 4; ++mi)
#pragma unroll
      for (int ni = 0; ni < 4; ++ni)
        acc[mi][ni] = __builtin_amdgcn_mfma_f32_16x16x32_bf16(af[mi], bf_[ni], acc[mi][ni], 0, 0, 0);
    __syncthreads();
  }

  // Epilogue: bias + exact gelu -> h bf16. Mask tail rows (prevents cross-expert races).
#pragma unroll
  for (int mi = 0; mi < 4; ++mi) {
    int rl = wr * 64 + mi * 16 + g * 4;
#pragma unroll
    for (int i = 0; i < 4; ++i) {
      int r = mt * 128 + rl + i;
      if (r < Me) {
        unsigned short* hrow = h + (size_t)(base + r) * DFF;
#pragma unroll
        for (int ni = 0; ni < 4; ++ni) {
          int col = n0 + wc * 64 + ni * 16 + fr;
          float v = acc[mi][ni][i] + bfc[e * DFF + col];
          hrow[col] = f2bf(gelu_f(v));
        }
      }
    }
  }
}

// ---------------- GEMM2: out += gate * (h @ wproj[e] + bproj[e]) ----------------
__global__ __launch_bounds__(256, 2) void gemm2_k(
    const unsigned short* __restrict__ h, const float* __restrict__ wproj,
    const float* __restrict__ bproj, const int* __restrict__ cnt,
    const int* __restrict__ off, const int* __restrict__ tok,
    const float* __restrict__ gate, float* __restrict__ out) {
  int bid = blockIdx.x;
  int mt = bid & 63;
  int nt = (bid >> 6) & 7;
  int e = bid >> 9;
  int Me = cnt[e];
  if (mt * 128 >= Me) return;
  int base = off[e];
  int n0 = nt * 128;

  __shared__ __align__(16) unsigned short Als[128][40];
  __shared__ __align__(16) unsigned short Bls[128][40];

  int tid = threadIdx.x;
  int rowA = tid >> 1, halfA = tid & 1;
  // rows beyond Me read neighbor/pad rows (in-bounds, h padded +128 rows); masked at store
  const unsigned short* srcA = h + (size_t)(base + mt * 128 + rowA) * DFF + halfA * 16;
  unsigned short* wA = &Als[rowA][halfA * 16];
  int nB = tid & 127, khB = tid >> 7;
  const float* srcB = wproj + (size_t)e * DFF * DMODEL + (size_t)(khB * 16) * DMODEL + n0 + nB;
  unsigned short* wB = &Bls[nB][khB * 16];

  int lane = tid & 63;
  int w = tid >> 6;
  int wr = w >> 1, wc = w & 1;
  int g = lane >> 4, fr = lane & 15;
  const unsigned short* rA[4];
  const unsigned short* rB[4];
#pragma unroll
  for (int i = 0; i < 4; ++i) {
    rA[i] = &Als[wr * 64 + i * 16 + fr][g * 8];
    rB[i] = &Bls[wc * 64 + i * 16 + fr][g * 8];
  }
  f32x4 acc[4][4];
#pragma unroll
  for (int i = 0; i < 4; ++i)
#pragma unroll
    for (int j = 0; j < 4; ++j) acc[i][j] = (f32x4)0.0f;

#pragma unroll 1
  for (int k0 = 0; k0 < DFF; k0 += 32) {
    const short8* pa = (const short8*)(srcA + k0);
    short8 A0 = pa[0], A1 = pa[1];  // h already bf16
    float vb[16];
#pragma unroll
    for (int j = 0; j < 16; ++j) vb[j] = srcB[(size_t)(k0 + j) * DMODEL];
    short8 B0 = pack8(vb[0], vb[1], vb[2], vb[3], vb[4], vb[5], vb[6], vb[7]);
    short8 B1 = pack8(vb[8], vb[9], vb[10], vb[11], vb[12], vb[13], vb[14], vb[15]);
    *(short8*)wA = A0; *(short8*)(wA + 8) = A1;
    *(short8*)wB = B0; *(short8*)(wB + 8) = B1;
    __syncthreads();
    short8 af[4], bf_[4];
#pragma unroll
    for (int i = 0; i < 4; ++i) af[i] = *(const short8*)rA[i];
#pragma unroll
    for (int i = 0; i < 4; ++i) bf_[i] = *(const short8*)rB[i];
#pragma unroll
    for (int mi = 0; mi < 4; ++mi)
#pragma unroll
      for (int ni = 0; ni < 4; ++ni)
        acc[mi][ni] = __builtin_amdgcn_mfma_f32_16x16x32_bf16(af[mi], bf_[ni], acc[mi][ni], 0, 0, 0);
    __syncthreads();
  }

  // Epilogue: out[tok] += gate * (acc + bproj). Exactly 2 commutative fp32 adds
  // per output element -> deterministic.
#pragma unroll
  for (int mi = 0; mi < 4; ++mi) {
    int rl = wr * 64 + mi * 16 + g * 4;
#pragma unroll
    for (int i = 0; i < 4; ++i) {
      int r = mt * 128 + rl + i;
      if (r < Me) {
        int tkn = tok[e * CAP + r];
        float gv = gate[e * CAP + r];
        float* orow = out + (size_t)tkn * DMODEL;
#pragma unroll
        for (int ni = 0; ni < 4; ++ni) {
          int col = n0 + wc * 64 + ni * 16 + fr;
          float v = acc[mi][ni][i] + bproj[e * DMODEL + col];
          atomicAdd(orow + col, gv * v);
        }
      }
    }
  }
}

extern "C" void kernel_launch(void* const* d_in, const int* in_sizes, int n_in,
                              void* d_out, int out_size, void* d_ws, size_t ws_size,
                              hipStream_t stream) {
  const float* x = (const float*)d_in[0];
  const float* rw = (const float*)d_in[1];
  const float* wfc = (const float*)d_in[2];
  const float* bfc = (const float*)d_in[3];
  const float* wproj = (const float*)d_in[4];
  const float* bproj = (const float*)d_in[5];
  float* out = (float*)d_out;

  char* ws = (char*)d_ws;
  int* cnt = (int*)ws;                     // 8 ints
  int* off = (int*)(ws + 64);              // 8 ints
  int* tok = (int*)(ws + 4096);            // 8*8192 ints
  float* gate = (float*)(ws + 4096 + (size_t)NEXP * CAP * 4);
  unsigned short* h = (unsigned short*)(ws + 4096 + 2 * (size_t)NEXP * CAP * 4);
  size_t need = 4096 + 2 * (size_t)NEXP * CAP * 4 + (size_t)(16384 + 128) * DFF * 2;
  fprintf(stderr, "[moe] ws_size=%zu need=%zu\n", ws_size, need);
  if (ws_size < need) {
    fprintf(stderr, "[moe] INSUFFICIENT WORKSPACE\n");
    return;
  }

  hipMemsetAsync(cnt, 0, 128, stream);
  hipMemsetAsync(out, 0, (size_t)out_size * 4, stream);
  router_k<<<N_TOK / 4, 256, 0, stream>>>(x, rw, cnt, tok, gate);
  prefix_k<<<1, 64, 0, stream>>>(cnt, off);
  gemm1_k<<<NEXP * 32 * 64, 256, 0, stream>>>(x, wfc, bfc, cnt, off, tok, h);
  gemm2_k<<<NEXP * 8 * 64, 256, 0, stream>>>(h, wproj, bproj, cnt, off, tok, gate, out);
}

// Round 3
// 1192.109 us; speedup vs baseline: 1.1575x; 1.1575x over previous
//
#include <hip/hip_runtime.h>
#include <hip/hip_bf16.h>

// MoE MLP (top-2 of 8 experts), D=1024, FF=4096, 8192 tokens, fp32 in/out.
// Pre-convert x + weights to bf16 (weights transposed to [N][K]) once per
// launch, then reg-double-buffered MFMA grouped GEMMs (one barrier/K-step).
// ws requirement ~210MB proven available in round 2.

#define N_TOK 8192
#define DMODEL 1024
#define NEXP 8
#define DFF 4096
#define CAP 8192

typedef __attribute__((ext_vector_type(8))) short short8;
typedef __attribute__((ext_vector_type(4))) float f32x4;

__device__ __forceinline__ unsigned short f2bf(float f) {
  unsigned u = __float_as_uint(f);
  return (unsigned short)((u + 0x7FFFu + ((u >> 16) & 1u)) >> 16);  // RNE
}

__device__ __forceinline__ float gelu_f(float v) {
  return 0.5f * v * (1.0f + erff(v * 0.70710678118654752f));
}

__device__ __forceinline__ short8 pack8(float f0, float f1, float f2, float f3,
                                        float f4, float f5, float f6, float f7) {
  short8 r;
  r[0] = (short)f2bf(f0); r[1] = (short)f2bf(f1);
  r[2] = (short)f2bf(f2); r[3] = (short)f2bf(f3);
  r[4] = (short)f2bf(f4); r[5] = (short)f2bf(f5);
  r[6] = (short)f2bf(f6); r[7] = (short)f2bf(f7);
  return r;
}

// ---------------- Router: 1 wave per token ----------------
__global__ void router_k(const float* __restrict__ x, const float* __restrict__ rw,
                         int* __restrict__ cnt, int* __restrict__ tok,
                         float* __restrict__ gate) {
  int lane = threadIdx.x & 63;
  int t = blockIdx.x * 4 + (threadIdx.x >> 6);
  const float* xr = x + (size_t)t * DMODEL;
  float p[8];
#pragma unroll
  for (int e = 0; e < 8; ++e) p[e] = 0.0f;
#pragma unroll
  for (int j = 0; j < DMODEL / 64; ++j) {
    int i = lane + j * 64;
    float xv = xr[i];
    const float4* r = (const float4*)(rw + (size_t)i * 8);
    float4 a = r[0], b = r[1];
    p[0] += xv * a.x; p[1] += xv * a.y; p[2] += xv * a.z; p[3] += xv * a.w;
    p[4] += xv * b.x; p[5] += xv * b.y; p[6] += xv * b.z; p[7] += xv * b.w;
  }
#pragma unroll
  for (int e = 0; e < 8; ++e) {
#pragma unroll
    for (int off = 32; off; off >>= 1) p[e] += __shfl_xor(p[e], off, 64);
  }
  if (lane == 0) {
    int e1 = 0;
#pragma unroll
    for (int e = 1; e < 8; ++e) if (p[e] > p[e1]) e1 = e;
    int e2 = (e1 == 0) ? 1 : 0;
#pragma unroll
    for (int e = 0; e < 8; ++e) if (e != e1 && p[e] > p[e2]) e2 = e;
    float w1 = 1.0f / (1.0f + expf(p[e2] - p[e1]));
    float w2 = 1.0f - w1;
    int s1 = atomicAdd(&cnt[e1], 1);
    tok[e1 * CAP + s1] = t; gate[e1 * CAP + s1] = w1;
    int s2 = atomicAdd(&cnt[e2], 1);
    tok[e2 * CAP + s2] = t; gate[e2 * CAP + s2] = w2;
  }
}

__global__ void prefix_k(const int* __restrict__ cnt, int* __restrict__ off) {
  if (threadIdx.x == 0 && blockIdx.x == 0) {
    int s = 0;
    for (int e = 0; e < NEXP; ++e) { off[e] = s; s += cnt[e]; }
  }
}

// ---------------- converts ----------------
__global__ void cvt_x_k(const float* __restrict__ x, unsigned short* __restrict__ xb) {
  int i = (blockIdx.x * 256 + threadIdx.x) * 8;
  const float4* p = (const float4*)(x + i);
  float4 a = p[0], b = p[1];
  *(short8*)(xb + i) = pack8(a.x, a.y, a.z, a.w, b.x, b.y, b.z, b.w);
}

// W [E][K][N] fp32 -> WT [E][N][K] bf16 (64x64 tile LDS transpose)
__global__ __launch_bounds__(256) void cvt_wt_k(const float* __restrict__ W,
                                                unsigned short* __restrict__ WT,
                                                int K, int N) {
  __shared__ float ls[64][68];
  int b = blockIdx.x;
  int nkt = K >> 6, nnt = N >> 6;
  int kt = b % nkt;
  int nt = (b / nkt) % nnt;
  int e = b / (nkt * nnt);
  const float* Wb = W + (size_t)e * K * N + (size_t)(kt * 64) * N + nt * 64;
  int t = threadIdx.x;
  int nn = (t & 15) * 4, kr = t >> 4;
#pragma unroll
  for (int i = 0; i < 4; ++i) {
    float4 v = *(const float4*)(Wb + (size_t)(kr + 16 * i) * N + nn);
    *(float4*)&ls[kr + 16 * i][nn] = v;
  }
  __syncthreads();
  int on = t >> 2, kc = (t & 3) * 16;
  unsigned short* dst = WT + (size_t)e * N * K + (size_t)(nt * 64 + on) * K + kt * 64 + kc;
  short8 r0, r1;
#pragma unroll
  for (int j = 0; j < 8; ++j) r0[j] = (short)f2bf(ls[kc + j][on]);
#pragma unroll
  for (int j = 0; j < 8; ++j) r1[j] = (short)f2bf(ls[kc + 8 + j][on]);
  *(short8*)dst = r0;
  *(short8*)(dst + 8) = r1;
}

// ---------------- GEMM1: h = gelu(Xb_gathered @ wfcT + bfc) ----------------
// 128x128 tile, BK=32, double-buffered LDS, one barrier per K-step.
// Staging: thread -> (row = tid>>1, k-half = tid&1), TWO short8 (32B) per
// matrix per K-step (full 16-elem k-slice; round-2 bug was staging only 8).
__global__ __launch_bounds__(256, 3) void gemm1a_k(
    const unsigned short* __restrict__ xb, const unsigned short* __restrict__ wT,
    const float* __restrict__ bfc, const int* __restrict__ cnt,
    const int* __restrict__ off, const int* __restrict__ tok,
    unsigned short* __restrict__ h) {
  int bid = blockIdx.x;
  int mt = bid & 63;
  int nt = (bid >> 6) & 31;
  int e = bid >> 11;
  int Me = cnt[e];
  if (mt * 128 >= Me) return;
  int base = off[e];
  int n0 = nt * 128;

  __shared__ __align__(16) unsigned short Als[2][128][40];
  __shared__ __align__(16) unsigned short Bls[2][128][40];

  int tid = threadIdx.x;
  int row = tid >> 1, half = tid & 1;
  int tIdx = mt * 128 + row;
  int tokn = tok[e * CAP + ((tIdx < Me) ? tIdx : (Me - 1))];
  const unsigned short* srcA = xb + (size_t)tokn * DMODEL + half * 16;
  const unsigned short* srcB = wT + ((size_t)e * DFF + n0 + row) * DMODEL + half * 16;

  int lane = tid & 63, w = tid >> 6;
  int wr = w >> 1, wc = w & 1;
  int g = lane >> 4, fr = lane & 15;

  f32x4 acc[4][4];
#pragma unroll
  for (int i = 0; i < 4; ++i)
#pragma unroll
    for (int j = 0; j < 4; ++j) acc[i][j] = (f32x4)0.0f;

  short8 ar0 = *(const short8*)srcA;
  short8 ar1 = *(const short8*)(srcA + 8);
  short8 br0 = *(const short8*)srcB;
  short8 br1 = *(const short8*)(srcB + 8);
  int cur = 0;
#pragma unroll 1
  for (int k0 = 0; k0 < DMODEL; k0 += 32) {
    *(short8*)&Als[cur][row][half * 16] = ar0;
    *(short8*)&Als[cur][row][half * 16 + 8] = ar1;
    *(short8*)&Bls[cur][row][half * 16] = br0;
    *(short8*)&Bls[cur][row][half * 16 + 8] = br1;
    if (k0 + 32 < DMODEL) {
      ar0 = *(const short8*)(srcA + k0 + 32);
      ar1 = *(const short8*)(srcA + k0 + 40);
      br0 = *(const short8*)(srcB + k0 + 32);
      br1 = *(const short8*)(srcB + k0 + 40);
    }
    __syncthreads();
    short8 af[4], bfv[4];
#pragma unroll
    for (int i = 0; i < 4; ++i) af[i] = *(const short8*)&Als[cur][wr * 64 + i * 16 + fr][g * 8];
#pragma unroll
    for (int i = 0; i < 4; ++i) bfv[i] = *(const short8*)&Bls[cur][wc * 64 + i * 16 + fr][g * 8];
#pragma unroll
    for (int mi = 0; mi < 4; ++mi)
#pragma unroll
      for (int ni = 0; ni < 4; ++ni)
        acc[mi][ni] = __builtin_amdgcn_mfma_f32_16x16x32_bf16(af[mi], bfv[ni], acc[mi][ni], 0, 0, 0);
    cur ^= 1;
  }

#pragma unroll
  for (int mi = 0; mi < 4; ++mi) {
    int rl = wr * 64 + mi * 16 + g * 4;
#pragma unroll
    for (int i = 0; i < 4; ++i) {
      int r = mt * 128 + rl + i;
      if (r < Me) {
        unsigned short* hrow = h + (size_t)(base + r) * DFF;
#pragma unroll
        for (int ni = 0; ni < 4; ++ni) {
          int col = n0 + wc * 64 + ni * 16 + fr;
          float v = acc[mi][ni][i] + bfc[e * DFF + col];
          hrow[col] = f2bf(gelu_f(v));
        }
      }
    }
  }
}

// ---------------- GEMM2: out += gate * (h @ wprojT + bproj) ----------------
__global__ __launch_bounds__(256, 3) void gemm2a_k(
    const unsigned short* __restrict__ h, const unsigned short* __restrict__ wT,
    const float* __restrict__ bproj, const int* __restrict__ cnt,
    const int* __restrict__ off, const int* __restrict__ tok,
    const float* __restrict__ gate, float* __restrict__ out) {
  int bid = blockIdx.x;
  int mt = bid & 63;
  int nt = (bid >> 6) & 7;
  int e = bid >> 9;
  int Me = cnt[e];
  if (mt * 128 >= Me) return;
  int base = off[e];
  int n0 = nt * 128;

  __shared__ __align__(16) unsigned short Als[2][128][40];
  __shared__ __align__(16) unsigned short Bls[2][128][40];

  int tid = threadIdx.x;
  int row = tid >> 1, half = tid & 1;
  // rows beyond Me read following rows (in-bounds: h padded +128 rows); masked at store
  const unsigned short* srcA = h + (size_t)(base + mt * 128 + row) * DFF + half * 16;
  const unsigned short* srcB = wT + ((size_t)e * DMODEL + n0 + row) * DFF + half * 16;

  int lane = tid & 63, w = tid >> 6;
  int wr = w >> 1, wc = w & 1;
  int g = lane >> 4, fr = lane & 15;

  f32x4 acc[4][4];
#pragma unroll
  for (int i = 0; i < 4; ++i)
#pragma unroll
    for (int j = 0; j < 4; ++j) acc[i][j] = (f32x4)0.0f;

  short8 ar0 = *(const short8*)srcA;
  short8 ar1 = *(const short8*)(srcA + 8);
  short8 br0 = *(const short8*)srcB;
  short8 br1 = *(const short8*)(srcB + 8);
  int cur = 0;
#pragma unroll 1
  for (int k0 = 0; k0 < DFF; k0 += 32) {
    *(short8*)&Als[cur][row][half * 16] = ar0;
    *(short8*)&Als[cur][row][half * 16 + 8] = ar1;
    *(short8*)&Bls[cur][row][half * 16] = br0;
    *(short8*)&Bls[cur][row][half * 16 + 8] = br1;
    if (k0 + 32 < DFF) {
      ar0 = *(const short8*)(srcA + k0 + 32);
      ar1 = *(const short8*)(srcA + k0 + 40);
      br0 = *(const short8*)(srcB + k0 + 32);
      br1 = *(const short8*)(srcB + k0 + 40);
    }
    __syncthreads();
    short8 af[4], bfv[4];
#pragma unroll
    for (int i = 0; i < 4; ++i) af[i] = *(const short8*)&Als[cur][wr * 64 + i * 16 + fr][g * 8];
#pragma unroll
    for (int i = 0; i < 4; ++i) bfv[i] = *(const short8*)&Bls[cur][wc * 64 + i * 16 + fr][g * 8];
#pragma unroll
    for (int mi = 0; mi < 4; ++mi)
#pragma unroll
      for (int ni = 0; ni < 4; ++ni)
        acc[mi][ni] = __builtin_amdgcn_mfma_f32_16x16x32_bf16(af[mi], bfv[ni], acc[mi][ni], 0, 0, 0);
    cur ^= 1;
  }

#pragma unroll
  for (int mi = 0; mi < 4; ++mi) {
    int rl = wr * 64 + mi * 16 + g * 4;
#pragma unroll
    for (int i = 0; i < 4; ++i) {
      int r = mt * 128 + rl + i;
      if (r < Me) {
        int tkn = tok[e * CAP + r];
        float gv = gate[e * CAP + r];
        float* orow = out + (size_t)tkn * DMODEL;
#pragma unroll
        for (int ni = 0; ni < 4; ++ni) {
          int col = n0 + wc * 64 + ni * 16 + fr;
          float v = acc[mi][ni][i] + bproj[e * DMODEL + col];
          atomicAdd(orow + col, gv * v);
        }
      }
    }
  }
}

extern "C" void kernel_launch(void* const* d_in, const int* in_sizes, int n_in,
                              void* d_out, int out_size, void* d_ws, size_t ws_size,
                              hipStream_t stream) {
  const float* x = (const float*)d_in[0];
  const float* rw = (const float*)d_in[1];
  const float* wfc = (const float*)d_in[2];
  const float* bfc = (const float*)d_in[3];
  const float* wproj = (const float*)d_in[4];
  const float* bproj = (const float*)d_in[5];
  float* out = (float*)d_out;

  char* ws = (char*)d_ws;
  int* cnt = (int*)ws;
  int* off_ = (int*)(ws + 64);
  int* tok = (int*)(ws + 4096);
  float* gate = (float*)(ws + 4096 + (size_t)NEXP * CAP * 4);
  size_t HOFF = 4096 + 2 * (size_t)NEXP * CAP * 4;
  unsigned short* h = (unsigned short*)(ws + HOFF);
  size_t HSZ = (size_t)(16384 + 128) * DFF * 2;
  size_t XOFF = HOFF + HSZ;
  size_t WOFF = XOFF + (size_t)N_TOK * DMODEL * 2;
  unsigned short* xb = (unsigned short*)(ws + XOFF);
  unsigned short* wT = (unsigned short*)(ws + WOFF);  // reused: wfcT then wprojT

  hipMemsetAsync(cnt, 0, 128, stream);
  hipMemsetAsync(out, 0, (size_t)out_size * 4, stream);
  router_k<<<N_TOK / 4, 256, 0, stream>>>(x, rw, cnt, tok, gate);
  prefix_k<<<1, 64, 0, stream>>>(cnt, off_);
  cvt_x_k<<<(N_TOK * DMODEL) / (8 * 256), 256, 0, stream>>>(x, xb);
  cvt_wt_k<<<NEXP * (DMODEL / 64) * (DFF / 64), 256, 0, stream>>>(wfc, wT, DMODEL, DFF);
  gemm1a_k<<<NEXP * 32 * 64, 256, 0, stream>>>(xb, wT, bfc, cnt, off_, tok, h);
  cvt_wt_k<<<NEXP * (DFF / 64) * (DMODEL / 64), 256, 0, stream>>>(wproj, wT, DFF, DMODEL);
  gemm2a_k<<<NEXP * 8 * 64, 256, 0, stream>>>(h, wT, bproj, cnt, off_, tok, gate, out);
}

// Round 4
// 820.285 us; speedup vs baseline: 1.6822x; 1.4533x over previous
//
#include <hip/hip_runtime.h>
#include <hip/hip_bf16.h>

// MoE MLP (top-2 of 8 experts), D=1024, FF=4096, 8192 tokens, fp32 in/out.
// Pre-convert x + weights to bf16 (weights transposed to [N][K]), then
// m97-structure grouped GEMMs: global_load_lds direct staging into linear
// [128][32] LDS tiles, 2 barriers per K-step, implicit multi-wave overlap.

#define N_TOK 8192
#define DMODEL 1024
#define NEXP 8
#define DFF 4096
#define CAP 8192

typedef __attribute__((ext_vector_type(8))) short short8;
typedef __attribute__((ext_vector_type(4))) float f32x4;

#define GLOAD_LDS16(g, l)                                              \
  __builtin_amdgcn_global_load_lds(                                    \
      (const __attribute__((address_space(1))) unsigned int*)(g),      \
      (__attribute__((address_space(3))) unsigned int*)(l), 16, 0, 0)

__device__ __forceinline__ unsigned short f2bf(float f) {
  unsigned u = __float_as_uint(f);
  return (unsigned short)((u + 0x7FFFu + ((u >> 16) & 1u)) >> 16);  // RNE
}

__device__ __forceinline__ float gelu_f(float v) {
  return 0.5f * v * (1.0f + erff(v * 0.70710678118654752f));
}

__device__ __forceinline__ short8 pack8(float f0, float f1, float f2, float f3,
                                        float f4, float f5, float f6, float f7) {
  short8 r;
  r[0] = (short)f2bf(f0); r[1] = (short)f2bf(f1);
  r[2] = (short)f2bf(f2); r[3] = (short)f2bf(f3);
  r[4] = (short)f2bf(f4); r[5] = (short)f2bf(f5);
  r[6] = (short)f2bf(f6); r[7] = (short)f2bf(f7);
  return r;
}

// ---------------- Router: 1 wave per token ----------------
__global__ void router_k(const float* __restrict__ x, const float* __restrict__ rw,
                         int* __restrict__ cnt, int* __restrict__ tok,
                         float* __restrict__ gate) {
  int lane = threadIdx.x & 63;
  int t = blockIdx.x * 4 + (threadIdx.x >> 6);
  const float* xr = x + (size_t)t * DMODEL;
  float p[8];
#pragma unroll
  for (int e = 0; e < 8; ++e) p[e] = 0.0f;
#pragma unroll
  for (int j = 0; j < DMODEL / 64; ++j) {
    int i = lane + j * 64;
    float xv = xr[i];
    const float4* r = (const float4*)(rw + (size_t)i * 8);
    float4 a = r[0], b = r[1];
    p[0] += xv * a.x; p[1] += xv * a.y; p[2] += xv * a.z; p[3] += xv * a.w;
    p[4] += xv * b.x; p[5] += xv * b.y; p[6] += xv * b.z; p[7] += xv * b.w;
  }
#pragma unroll
  for (int e = 0; e < 8; ++e) {
#pragma unroll
    for (int off = 32; off; off >>= 1) p[e] += __shfl_xor(p[e], off, 64);
  }
  if (lane == 0) {
    int e1 = 0;
#pragma unroll
    for (int e = 1; e < 8; ++e) if (p[e] > p[e1]) e1 = e;
    int e2 = (e1 == 0) ? 1 : 0;
#pragma unroll
    for (int e = 0; e < 8; ++e) if (e != e1 && p[e] > p[e2]) e2 = e;
    float w1 = 1.0f / (1.0f + expf(p[e2] - p[e1]));
    float w2 = 1.0f - w1;
    int s1 = atomicAdd(&cnt[e1], 1);
    tok[e1 * CAP + s1] = t; gate[e1 * CAP + s1] = w1;
    int s2 = atomicAdd(&cnt[e2], 1);
    tok[e2 * CAP + s2] = t; gate[e2 * CAP + s2] = w2;
  }
}

__global__ void prefix_k(const int* __restrict__ cnt, int* __restrict__ off) {
  if (threadIdx.x == 0 && blockIdx.x == 0) {
    int s = 0;
    for (int e = 0; e < NEXP; ++e) { off[e] = s; s += cnt[e]; }
  }
}

// ---------------- converts ----------------
__global__ void cvt_x_k(const float* __restrict__ x, unsigned short* __restrict__ xb) {
  int i = (blockIdx.x * 256 + threadIdx.x) * 8;
  const float4* p = (const float4*)(x + i);
  float4 a = p[0], b = p[1];
  *(short8*)(xb + i) = pack8(a.x, a.y, a.z, a.w, b.x, b.y, b.z, b.w);
}

// W [E][K][N] fp32 -> WT [E][N][K] bf16 (64x64 tile LDS transpose)
__global__ __launch_bounds__(256) void cvt_wt_k(const float* __restrict__ W,
                                                unsigned short* __restrict__ WT,
                                                int K, int N) {
  __shared__ float ls[64][68];
  int b = blockIdx.x;
  int nkt = K >> 6, nnt = N >> 6;
  int kt = b % nkt;
  int nt = (b / nkt) % nnt;
  int e = b / (nkt * nnt);
  const float* Wb = W + (size_t)e * K * N + (size_t)(kt * 64) * N + nt * 64;
  int t = threadIdx.x;
  int nn = (t & 15) * 4, kr = t >> 4;
#pragma unroll
  for (int i = 0; i < 4; ++i) {
    float4 v = *(const float4*)(Wb + (size_t)(kr + 16 * i) * N + nn);
    *(float4*)&ls[kr + 16 * i][nn] = v;
  }
  __syncthreads();
  int on = t >> 2, kc = (t & 3) * 16;
  unsigned short* dst = WT + (size_t)e * N * K + (size_t)(nt * 64 + on) * K + kt * 64 + kc;
  short8 r0, r1;
#pragma unroll
  for (int j = 0; j < 8; ++j) r0[j] = (short)f2bf(ls[kc + j][on]);
#pragma unroll
  for (int j = 0; j < 8; ++j) r1[j] = (short)f2bf(ls[kc + 8 + j][on]);
  *(short8*)dst = r0;
  *(short8*)(dst + 8) = r1;
}

// ---------------- GEMM1: h = gelu(Xb_gathered @ wfcT + bfc) ----------------
// m97 structure: 128x128 tile, BK=32, linear LDS [128][32], global_load_lds,
// 2 barriers/K-step. Wave w stages rows [w*32, w*32+32) of both tiles.
__global__ __launch_bounds__(256, 4) void gemm1a_k(
    const unsigned short* __restrict__ xb, const unsigned short* __restrict__ wT,
    const float* __restrict__ bfc, const int* __restrict__ cnt,
    const int* __restrict__ off, const int* __restrict__ tok,
    unsigned short* __restrict__ h) {
  int bid = (int)(blockIdx.x & 7) * ((int)gridDim.x >> 3) + (int)(blockIdx.x >> 3);
  int mt = bid & 63;
  int nt = (bid >> 6) & 31;
  int e = bid >> 11;
  int Me = cnt[e];
  if (mt * 128 >= Me) return;
  int base = off[e];
  int n0 = nt * 128;

  __shared__ __align__(16) unsigned short As[128 * 32];
  __shared__ __align__(16) unsigned short Bs[128 * 32];

  int tid = threadIdx.x;
  int lane = tid & 63, w = tid >> 6;
  int lr = lane >> 2;            // row-within-16 for staging
  int lc = (lane & 3) * 8;       // k-offset (shorts) for staging

  // per-lane global srcs (two 16-row slabs per wave per matrix)
  int ar0i = mt * 128 + w * 32 + lr;
  int ar1i = ar0i + 16;
  int t0 = tok[e * CAP + ((ar0i < Me) ? ar0i : (Me - 1))];
  int t1 = tok[e * CAP + ((ar1i < Me) ? ar1i : (Me - 1))];
  const unsigned short* gA0 = xb + (size_t)t0 * DMODEL + lc;
  const unsigned short* gA1 = xb + (size_t)t1 * DMODEL + lc;
  const unsigned short* gB0 = wT + ((size_t)e * DFF + n0 + w * 32 + lr) * DMODEL + lc;
  const unsigned short* gB1 = gB0 + (size_t)16 * DMODEL;
  unsigned short* lA0 = &As[(w * 32) * 32];
  unsigned short* lA1 = &As[(w * 32 + 16) * 32];
  unsigned short* lB0 = &Bs[(w * 32) * 32];
  unsigned short* lB1 = &Bs[(w * 32 + 16) * 32];

  int wr = w >> 1, wc = w & 1;
  int g = lane >> 4, fr = lane & 15;

  f32x4 acc[4][4];
#pragma unroll
  for (int i = 0; i < 4; ++i)
#pragma unroll
    for (int j = 0; j < 4; ++j) acc[i][j] = (f32x4)0.0f;

#pragma unroll 1
  for (int k0 = 0; k0 < DMODEL; k0 += 32) {
    GLOAD_LDS16(gA0 + k0, lA0);
    GLOAD_LDS16(gA1 + k0, lA1);
    GLOAD_LDS16(gB0 + k0, lB0);
    GLOAD_LDS16(gB1 + k0, lB1);
    __syncthreads();
    short8 af[4], bfv[4];
#pragma unroll
    for (int i = 0; i < 4; ++i) af[i] = *(const short8*)&As[(wr * 64 + i * 16 + fr) * 32 + g * 8];
#pragma unroll
    for (int i = 0; i < 4; ++i) bfv[i] = *(const short8*)&Bs[(wc * 64 + i * 16 + fr) * 32 + g * 8];
#pragma unroll
    for (int mi = 0; mi < 4; ++mi)
#pragma unroll
      for (int ni = 0; ni < 4; ++ni)
        acc[mi][ni] = __builtin_amdgcn_mfma_f32_16x16x32_bf16(af[mi], bfv[ni], acc[mi][ni], 0, 0, 0);
    __syncthreads();
  }

#pragma unroll
  for (int mi = 0; mi < 4; ++mi) {
    int rl = wr * 64 + mi * 16 + g * 4;
#pragma unroll
    for (int i = 0; i < 4; ++i) {
      int r = mt * 128 + rl + i;
      if (r < Me) {
        unsigned short* hrow = h + (size_t)(base + r) * DFF;
#pragma unroll
        for (int ni = 0; ni < 4; ++ni) {
          int col = n0 + wc * 64 + ni * 16 + fr;
          float v = acc[mi][ni][i] + bfc[e * DFF + col];
          hrow[col] = f2bf(gelu_f(v));
        }
      }
    }
  }
}

// ---------------- GEMM2: out += gate * (h @ wprojT + bproj) ----------------
__global__ __launch_bounds__(256, 4) void gemm2a_k(
    const unsigned short* __restrict__ h, const unsigned short* __restrict__ wT,
    const float* __restrict__ bproj, const int* __restrict__ cnt,
    const int* __restrict__ off, const int* __restrict__ tok,
    const float* __restrict__ gate, float* __restrict__ out) {
  int bid = (int)(blockIdx.x & 7) * ((int)gridDim.x >> 3) + (int)(blockIdx.x >> 3);
  int mt = bid & 63;
  int nt = (bid >> 6) & 7;
  int e = bid >> 9;
  int Me = cnt[e];
  if (mt * 128 >= Me) return;
  int base = off[e];
  int n0 = nt * 128;

  __shared__ __align__(16) unsigned short As[128 * 32];
  __shared__ __align__(16) unsigned short Bs[128 * 32];

  int tid = threadIdx.x;
  int lane = tid & 63, w = tid >> 6;
  int lr = lane >> 2;
  int lc = (lane & 3) * 8;

  // A rows beyond Me read following rows (in-bounds: h padded +128); masked at store.
  const unsigned short* gA0 = h + (size_t)(base + mt * 128 + w * 32 + lr) * DFF + lc;
  const unsigned short* gA1 = gA0 + (size_t)16 * DFF;
  const unsigned short* gB0 = wT + ((size_t)e * DMODEL + n0 + w * 32 + lr) * DFF + lc;
  const unsigned short* gB1 = gB0 + (size_t)16 * DFF;
  unsigned short* lA0 = &As[(w * 32) * 32];
  unsigned short* lA1 = &As[(w * 32 + 16) * 32];
  unsigned short* lB0 = &Bs[(w * 32) * 32];
  unsigned short* lB1 = &Bs[(w * 32 + 16) * 32];

  int wr = w >> 1, wc = w & 1;
  int g = lane >> 4, fr = lane & 15;

  f32x4 acc[4][4];
#pragma unroll
  for (int i = 0; i < 4; ++i)
#pragma unroll
    for (int j = 0; j < 4; ++j) acc[i][j] = (f32x4)0.0f;

#pragma unroll 1
  for (int k0 = 0; k0 < DFF; k0 += 32) {
    GLOAD_LDS16(gA0 + k0, lA0);
    GLOAD_LDS16(gA1 + k0, lA1);
    GLOAD_LDS16(gB0 + k0, lB0);
    GLOAD_LDS16(gB1 + k0, lB1);
    __syncthreads();
    short8 af[4], bfv[4];
#pragma unroll
    for (int i = 0; i < 4; ++i) af[i] = *(const short8*)&As[(wr * 64 + i * 16 + fr) * 32 + g * 8];
#pragma unroll
    for (int i = 0; i < 4; ++i) bfv[i] = *(const short8*)&Bs[(wc * 64 + i * 16 + fr) * 32 + g * 8];
#pragma unroll
    for (int mi = 0; mi < 4; ++mi)
#pragma unroll
      for (int ni = 0; ni < 4; ++ni)
        acc[mi][ni] = __builtin_amdgcn_mfma_f32_16x16x32_bf16(af[mi], bfv[ni], acc[mi][ni], 0, 0, 0);
    __syncthreads();
  }

#pragma unroll
  for (int mi = 0; mi < 4; ++mi) {
    int rl = wr * 64 + mi * 16 + g * 4;
#pragma unroll
    for (int i = 0; i < 4; ++i) {
      int r = mt * 128 + rl + i;
      if (r < Me) {
        int tkn = tok[e * CAP + r];
        float gv = gate[e * CAP + r];
        float* orow = out + (size_t)tkn * DMODEL;
#pragma unroll
        for (int ni = 0; ni < 4; ++ni) {
          int col = n0 + wc * 64 + ni * 16 + fr;
          float v = acc[mi][ni][i] + bproj[e * DMODEL + col];
          atomicAdd(orow + col, gv * v);
        }
      }
    }
  }
}

extern "C" void kernel_launch(void* const* d_in, const int* in_sizes, int n_in,
                              void* d_out, int out_size, void* d_ws, size_t ws_size,
                              hipStream_t stream) {
  const float* x = (const float*)d_in[0];
  const float* rw = (const float*)d_in[1];
  const float* wfc = (const float*)d_in[2];
  const float* bfc = (const float*)d_in[3];
  const float* wproj = (const float*)d_in[4];
  const float* bproj = (const float*)d_in[5];
  float* out = (float*)d_out;

  char* ws = (char*)d_ws;
  int* cnt = (int*)ws;
  int* off_ = (int*)(ws + 64);
  int* tok = (int*)(ws + 4096);
  float* gate = (float*)(ws + 4096 + (size_t)NEXP * CAP * 4);
  size_t HOFF = 4096 + 2 * (size_t)NEXP * CAP * 4;
  unsigned short* h = (unsigned short*)(ws + HOFF);
  size_t HSZ = (size_t)(16384 + 128) * DFF * 2;
  size_t XOFF = HOFF + HSZ;
  size_t WOFF = XOFF + (size_t)N_TOK * DMODEL * 2;
  unsigned short* xb = (unsigned short*)(ws + XOFF);
  unsigned short* wT = (unsigned short*)(ws + WOFF);  // reused: wfcT then wprojT

  hipMemsetAsync(cnt, 0, 128, stream);
  hipMemsetAsync(out, 0, (size_t)out_size * 4, stream);
  router_k<<<N_TOK / 4, 256, 0, stream>>>(x, rw, cnt, tok, gate);
  prefix_k<<<1, 64, 0, stream>>>(cnt, off_);
  cvt_x_k<<<(N_TOK * DMODEL) / (8 * 256), 256, 0, stream>>>(x, xb);
  cvt_wt_k<<<NEXP * (DMODEL / 64) * (DFF / 64), 256, 0, stream>>>(wfc, wT, DMODEL, DFF);
  gemm1a_k<<<NEXP * 32 * 64, 256, 0, stream>>>(xb, wT, bfc, cnt, off_, tok, h);
  cvt_wt_k<<<NEXP * (DFF / 64) * (DMODEL / 64), 256, 0, stream>>>(wproj, wT, DFF, DMODEL);
  gemm2a_k<<<NEXP * 8 * 64, 256, 0, stream>>>(h, wT, bproj, cnt, off_, tok, gate, out);
}